// Round 1
// 101.439 us; speedup vs baseline: 1.0190x; 1.0190x over previous
//
#include <hip/hip_runtime.h>
#include <math.h>

#define B_ 8
#define N_ 256
#define H_ 128
#define NODES_ (B_ * N_)   // 2048

#define LOG2E 1.442695041f
#define LN2   0.6931471806f

__device__ __forceinline__ float silu_fast(float x) {
    float e = __expf(-x);
    return x * __builtin_amdgcn_rcpf(1.0f + e);
}

// split-K GEMM tile: 16 k-segments x (4 nodes x 128 cols), each thread owns
// (kseg = t>>5, c0 = (t&31)*4). Every weight float4 loaded by exactly one
// thread (no L2 amplification), activations via LDS b128 reads (2 per n vs
// 8 scalar broadcasts). Partials to pls for the 16-way reduce.
__device__ __forceinline__ void splitk_gemm(
    const float* __restrict__ Wb,         // W + kseg*8*H_ + c0
    const float (*actm)[128],             // [4][128] activations in LDS
    float (*pls)[4][128], int kseg, int c0)
{
    float4 w[8];
    #pragma unroll
    for (int u = 0; u < 8; ++u) w[u] = *(const float4*)(Wb + u * H_);
    #pragma unroll
    for (int n = 0; n < 4; ++n) {
        float vv[8];
        *(float4*)(vv)     = *(const float4*)(&actm[n][kseg * 8]);
        *(float4*)(vv + 4) = *(const float4*)(&actm[n][kseg * 8 + 4]);
        float4 a = {0.f, 0.f, 0.f, 0.f};
        #pragma unroll
        for (int u = 0; u < 8; ++u) {
            a.x = fmaf(vv[u], w[u].x, a.x);
            a.y = fmaf(vv[u], w[u].y, a.y);
            a.z = fmaf(vv[u], w[u].z, a.z);
            a.w = fmaf(vv[u], w[u].w, a.w);
        }
        *(float4*)(&pls[kseg][n][c0]) = a;
    }
}

// ---------------------------------------------------------------------------
// k1q: Q' = -log2e * (node @ We1b) + (1-m_j)*1e30        (grid 512, block 512)
// Pre-scaled into exp2 domain; masked j folds to +1e30 -> exp2=inf -> rcp=0.
// P and pre moved into k2 (block-local there).
// ---------------------------------------------------------------------------
__global__ __launch_bounds__(512) void k1q(
    const float* __restrict__ node, const float* __restrict__ We1,
    const float* __restrict__ mask, float* __restrict__ Q)
{
    __shared__ __align__(16) float act[4][128];
    __shared__ __align__(16) float pls[16][4][128];
    const int t = threadIdx.x;
    const int node0 = blockIdx.x * 4;

    if (t < 128) {
        int r = t >> 5, col = (t & 31) * 4;
        *(float4*)(&act[r][col]) = *(const float4*)(node + (size_t)(node0 + r) * H_ + col);
    }
    const int kseg = t >> 5;
    const int c0   = (t & 31) * 4;
    __syncthreads();

    splitk_gemm(We1 + (size_t)(128 + kseg * 8) * H_ + c0, act, pls, kseg, c0);
    __syncthreads();
    {
        const int n = t >> 7, c = t & 127;
        float s = 0.f;
        #pragma unroll
        for (int seg = 0; seg < 16; ++seg) s += pls[seg][n][c];
        const float m = mask[node0 + n];
        Q[(size_t)(node0 + n) * H_ + c] = fmaf(-LOG2E, s, (1.0f - m) * 1e30f);
    }
}

// ---------------------------------------------------------------------------
// k2: phase A (block-local P', pre) + edge loop + node epilogue.
// grid 512 (4 i/block), block 512.
// Phase A: P' = -log2e*(node@We1a + be1), pre = node@Wn1a + bn1 (LDS-resident;
//          Q chunk-0 prefetch issued first so HBM latency hides under it).
// Edge: thread = (i = t>>7, jq = (t>>5)&3, cg = t&31); 4 channels/thread via
//       ds_read_b128, 16 j per chunk per thread, jq-partials reduced in LDS.
//       Inner body (per 4 elems): b128 + b32 + 4x(add,fma,exp2,add,rcp,fma)
//       = 26 slots vs old 36.
// Epilogue: T = S'@We2 + mi*be2; hidden = silu(pre + T@Wn1b);
//           out = node + mi*(hidden@Wn2 + bn2).
// ---------------------------------------------------------------------------
__global__ __launch_bounds__(512) void k2(
    const float* __restrict__ Qv, const float* __restrict__ We1,
    const float* __restrict__ be1, const float* __restrict__ positions,
    const float* __restrict__ mask, const float* __restrict__ node,
    const float* __restrict__ We2, const float* __restrict__ be2,
    const float* __restrict__ Wn1, const float* __restrict__ bn1,
    const float* __restrict__ Wn2, const float* __restrict__ bn2,
    float* __restrict__ out)
{
    __shared__ __align__(16) float arena[8192];     // 32 KB: Q chunk | pls
    __shared__ __align__(16) float dls[256][4];
    __shared__ __align__(16) float Sls[4][128];
    __shared__ __align__(16) float Tls[4][128];     // act (phase A), then T
    __shared__ __align__(16) float Pls[4][128];     // P' (exp2-scaled)
    __shared__ __align__(16) float prels[4][128];   // pre
    __shared__ float cs;

    const int t  = threadIdx.x;
    const int b  = blockIdx.x >> 6;
    const int i0 = (blockIdx.x & 63) * 4;
    const int node0 = b * N_ + i0;

    // Q chunk-0 prefetch — issue before phase A so the latency hides there
    const float4* __restrict__ Qg = (const float4*)(Qv + (size_t)(b * N_) * H_);
    float4 r0 = Qg[0 * 512 + t];
    float4 r1 = Qg[1 * 512 + t];
    float4 r2 = Qg[2 * 512 + t];
    float4 r3 = Qg[3 * 512 + t];

    // pairwise distances for this block's 4 i-rows
    {
        const int t2 = t & 255;
        const int half = t >> 8;
        const int il = t2 & 3;
        const int jb = t2 >> 2;
        const float* pb = positions + b * N_ * 3;
        const float pix = pb[(i0 + il) * 3 + 0];
        const float piy = pb[(i0 + il) * 3 + 1];
        const float piz = pb[(i0 + il) * 3 + 2];
        #pragma unroll
        for (int s = 0; s < 2; ++s) {
            int j = jb + 64 * (half * 2 + s);
            float dx = pix - pb[j * 3 + 0];
            float dy = piy - pb[j * 3 + 1];
            float dz = piz - pb[j * 3 + 2];
            float sq = dx * dx + dy * dy + dz * dz;
            dls[j][il] = (sq > 0.f) ? sqrtf(sq) : 0.f;
        }
    }
    if (t < 64) {   // cnt = sum_j mask[b][j]
        float mv = mask[b * N_ + t] + mask[b * N_ + 64 + t]
                 + mask[b * N_ + 128 + t] + mask[b * N_ + 192 + t];
        #pragma unroll
        for (int off = 32; off >= 1; off >>= 1) mv += __shfl_down(mv, off);
        if (t == 0) cs = mv;
    }

    // ---- phase A: P' and pre for own 4 rows (arena = split-K partials) ----
    const int kseg = t >> 5;
    const int c0   = (t & 31) * 4;
    float (*pls)[4][128] = (float (*)[4][128])arena;

    if (t < 128) {
        int r = t >> 5, col = (t & 31) * 4;
        *(float4*)(&Tls[r][col]) = *(const float4*)(node + (size_t)(node0 + r) * H_ + col);
    }
    __syncthreads();
    splitk_gemm(We1 + (size_t)(kseg * 8) * H_ + c0, Tls, pls, kseg, c0);
    __syncthreads();
    {
        const int n = t >> 7, c = t & 127;
        float s = 0.f;
        #pragma unroll
        for (int seg = 0; seg < 16; ++seg) s += pls[seg][n][c];
        Pls[n][c] = -LOG2E * (s + be1[c]);
    }
    __syncthreads();
    splitk_gemm(Wn1 + (size_t)(kseg * 8) * H_ + c0, Tls, pls, kseg, c0);
    __syncthreads();
    {
        const int n = t >> 7, c = t & 127;
        float s = 0.f;
        #pragma unroll
        for (int seg = 0; seg < 16; ++seg) s += pls[seg][n][c];
        prels[n][c] = s + bn1[c];
    }
    // (pls reads vs chunk-0 staging writes fenced by the loop's first sync)

    // ---- edge loop ----
    const int i   = t >> 7;          // wave-uniform
    const int jq  = (t >> 5) & 3;    // j-quarter within chunk
    const int cg  = t & 31;
    const int c0e = cg * 4;

    float4 wd4 = *(const float4*)(We1 + (size_t)256 * H_ + c0e);
    wd4.x *= -LOG2E; wd4.y *= -LOG2E; wd4.z *= -LOG2E; wd4.w *= -LOG2E;
    const float4 base4 = *(const float4*)(&Pls[i][c0e]);   // safe: synced above
    float4 acc = {0.f, 0.f, 0.f, 0.f};

    for (int ch = 0; ch < 4; ++ch) {
        __syncthreads();              // previous chunk compute / pls reads done
        ((float4*)arena)[0 * 512 + t] = r0;
        ((float4*)arena)[1 * 512 + t] = r1;
        ((float4*)arena)[2 * 512 + t] = r2;
        ((float4*)arena)[3 * 512 + t] = r3;
        if (ch < 3) {                 // prefetch next chunk during compute
            r0 = Qg[(ch + 1) * 2048 + 0 * 512 + t];
            r1 = Qg[(ch + 1) * 2048 + 1 * 512 + t];
            r2 = Qg[(ch + 1) * 2048 + 2 * 512 + t];
            r3 = Qg[(ch + 1) * 2048 + 3 * 512 + t];
        }
        __syncthreads();              // staging visible
        const float4* qrow = ((const float4*)arena) + (jq * 16) * 32 + cg;
        const int jd = ch * 64 + jq * 16;
        #pragma unroll 8
        for (int jj = 0; jj < 16; ++jj) {
            float4 q = qrow[jj * 32];           // ds_read_b128, conflict-free
            float d  = dls[jd + jj][i];          // broadcast
            float nx = fmaf(d, wd4.x, base4.x + q.x);   // ny = -log2e * x
            float ny = fmaf(d, wd4.y, base4.y + q.y);
            float nz = fmaf(d, wd4.z, base4.z + q.z);
            float nw = fmaf(d, wd4.w, base4.w + q.w);
            float ex = __builtin_amdgcn_exp2f(nx);      // e^{-x}
            float ey = __builtin_amdgcn_exp2f(ny);
            float ez = __builtin_amdgcn_exp2f(nz);
            float ew = __builtin_amdgcn_exp2f(nw);
            acc.x = fmaf(nx, __builtin_amdgcn_rcpf(1.0f + ex), acc.x);
            acc.y = fmaf(ny, __builtin_amdgcn_rcpf(1.0f + ey), acc.y);
            acc.z = fmaf(nz, __builtin_amdgcn_rcpf(1.0f + ez), acc.z);
            acc.w = fmaf(nw, __builtin_amdgcn_rcpf(1.0f + ew), acc.w);
            // masked j: n* ~ +1e30 -> exp2=inf -> rcp=0 -> fma adds exact 0
        }
    }

    __syncthreads();                  // last chunk's arena reads done
    {   // reduce jq-partials: acc holds -log2e * sum_j x*sigmoid(x)
        float (*pq)[4][128] = (float (*)[4][128])arena;   // [4][4][128]
        *(float4*)(&pq[jq][i][c0e]) = acc;
    }
    __syncthreads();
    const float mi = mask[node0 + i];
    {
        const int c = t & 127;
        float (*pq)[4][128] = (float (*)[4][128])arena;
        float s = pq[0][i][c] + pq[1][i][c] + pq[2][i][c] + pq[3][i][c];
        const float inv_cnt = __builtin_amdgcn_rcpf(fmaxf(cs, 1.0f));
        Sls[i][c] = (mi * inv_cnt * -LN2) * s;     // unscale exp2 domain
    }
    __syncthreads();

    // ---- epilogue: 3 split-K GEMMs, arena = partials ----
    // G1: T = S' @ We2 + mi*be2
    splitk_gemm(We2 + (size_t)(kseg * 8) * H_ + c0, Sls, pls, kseg, c0);
    __syncthreads();
    {
        const int c = t & 127;
        float s = 0.f;
        #pragma unroll
        for (int seg = 0; seg < 16; ++seg) s += pls[seg][i][c];
        Tls[i][c] = fmaf(mi, be2[c], s);
    }
    __syncthreads();

    // G2: hidden = silu(pre + T @ Wn1[128:])
    splitk_gemm(Wn1 + (size_t)(128 + kseg * 8) * H_ + c0, Tls, pls, kseg, c0);
    __syncthreads();
    {
        const int c = t & 127;
        float s = 0.f;
        #pragma unroll
        for (int seg = 0; seg < 16; ++seg) s += pls[seg][i][c];
        Sls[i][c] = silu_fast(prels[i][c] + s);    // reuse Sls as hidden
    }
    __syncthreads();

    // G3: out = node + mi * (hidden @ Wn2 + bn2)
    splitk_gemm(Wn2 + (size_t)(kseg * 8) * H_ + c0, Sls, pls, kseg, c0);
    __syncthreads();
    {
        const int c = t & 127;
        float s = 0.f;
        #pragma unroll
        for (int seg = 0; seg < 16; ++seg) s += pls[seg][i][c];
        const size_t idx = (size_t)(node0 + i) * H_ + c;
        out[idx] = node[idx] + mi * (s + bn2[c]);
    }
}

extern "C" void kernel_launch(void* const* d_in, const int* in_sizes, int n_in,
                              void* d_out, int out_size, void* d_ws, size_t ws_size,
                              hipStream_t stream)
{
    const float* node      = (const float*)d_in[0];
    const float* positions = (const float*)d_in[1];
    const float* mask      = (const float*)d_in[2];
    const float* We1       = (const float*)d_in[3];
    const float* be1       = (const float*)d_in[4];
    const float* We2       = (const float*)d_in[5];
    const float* be2       = (const float*)d_in[6];
    const float* Wn1       = (const float*)d_in[7];
    const float* bn1       = (const float*)d_in[8];
    const float* Wn2       = (const float*)d_in[9];
    const float* bn2       = (const float*)d_in[10];
    float* out = (float*)d_out;

    float* Q = (float*)d_ws;                   // 1 MB (was 3 MB)

    k1q<<<512, 512, 0, stream>>>(node, We1, mask, Q);
    k2 <<<512, 512, 0, stream>>>(Q, We1, be1, positions, mask, node,
                                 We2, be2, Wn1, bn1, Wn2, bn2, out);
}

// Round 2
// 100.362 us; speedup vs baseline: 1.0300x; 1.0107x over previous
//
#include <hip/hip_runtime.h>
#include <math.h>

#define B_ 8
#define N_ 256
#define H_ 128
#define NODES_ (B_ * N_)   // 2048

#define LOG2E 1.442695041f
#define LN2   0.6931471806f

__device__ __forceinline__ float silu_fast(float x) {
    float e = __expf(-x);
    return x * __builtin_amdgcn_rcpf(1.0f + e);
}

// split-K GEMM tile: 16 k-segments x (4 nodes x 128 cols), each thread owns
// (kseg = t>>5, c0 = (t&31)*4). Every weight float4 loaded by exactly one
// thread (no L2 amplification), activations via LDS b128 reads. Partials to
// pls for the 16-way reduce.
__device__ __forceinline__ void splitk_gemm(
    const float* __restrict__ Wb,         // W + kseg*8*H_ + c0
    const float (*actm)[128],             // [4][128] activations in LDS
    float (*pls)[4][128], int kseg, int c0)
{
    float4 w[8];
    #pragma unroll
    for (int u = 0; u < 8; ++u) w[u] = *(const float4*)(Wb + u * H_);
    #pragma unroll
    for (int n = 0; n < 4; ++n) {
        float vv[8];
        *(float4*)(vv)     = *(const float4*)(&actm[n][kseg * 8]);
        *(float4*)(vv + 4) = *(const float4*)(&actm[n][kseg * 8 + 4]);
        float4 a = {0.f, 0.f, 0.f, 0.f};
        #pragma unroll
        for (int u = 0; u < 8; ++u) {
            a.x = fmaf(vv[u], w[u].x, a.x);
            a.y = fmaf(vv[u], w[u].y, a.y);
            a.z = fmaf(vv[u], w[u].z, a.z);
            a.w = fmaf(vv[u], w[u].w, a.w);
        }
        *(float4*)(&pls[kseg][n][c0]) = a;
    }
}

// ---------------------------------------------------------------------------
// k1q: Q' = -log2e * (node @ We1b) + (1-m_j)*1e30        (grid 512, block 512)
// Pre-scaled into exp2 domain; masked j folds to +1e30 -> exp2=inf -> rcp=0.
// ---------------------------------------------------------------------------
__global__ __launch_bounds__(512) void k1q(
    const float* __restrict__ node, const float* __restrict__ We1,
    const float* __restrict__ mask, float* __restrict__ Q)
{
    __shared__ __align__(16) float act[4][128];
    __shared__ __align__(16) float pls[16][4][128];
    const int t = threadIdx.x;
    const int node0 = blockIdx.x * 4;

    if (t < 128) {
        int r = t >> 5, col = (t & 31) * 4;
        *(float4*)(&act[r][col]) = *(const float4*)(node + (size_t)(node0 + r) * H_ + col);
    }
    const int kseg = t >> 5;
    const int c0   = (t & 31) * 4;
    __syncthreads();

    splitk_gemm(We1 + (size_t)(128 + kseg * 8) * H_ + c0, act, pls, kseg, c0);
    __syncthreads();
    {
        const int n = t >> 7, c = t & 127;
        float s = 0.f;
        #pragma unroll
        for (int seg = 0; seg < 16; ++seg) s += pls[seg][n][c];
        const float m = mask[node0 + n];
        Q[(size_t)(node0 + n) * H_ + c] = fmaf(-LOG2E, s, (1.0f - m) * 1e30f);
    }
}

// ---------------------------------------------------------------------------
// k2: phase A (block-local P', pre) + edge loop + node epilogue.
// grid 512 (4 i/block), block 512.
// Edge re-decomposition (R2): thread = (jh = t>>5, cg = t&31); each thread
// owns 4 channels x ALL 4 i-rows x 16 j's (jh-strided). Q read ONCE per
// element straight from global (L2-resident; no LDS staging — each element
// now has exactly one consumer). d[j][0..3] arrives as one b128 broadcast.
// Edge loop is trans-pipe bound (2 trans/elem); LDS traffic ~6x lower.
// 16-way jh-partial reduce through arena afterwards.
// ---------------------------------------------------------------------------
__global__ __launch_bounds__(512) void k2(
    const float* __restrict__ Qv, const float* __restrict__ We1,
    const float* __restrict__ be1, const float* __restrict__ positions,
    const float* __restrict__ mask, const float* __restrict__ node,
    const float* __restrict__ We2, const float* __restrict__ be2,
    const float* __restrict__ Wn1, const float* __restrict__ bn1,
    const float* __restrict__ Wn2, const float* __restrict__ bn2,
    float* __restrict__ out)
{
    __shared__ __align__(16) float arena[8192];     // 32 KB: split-K / jh partials
    __shared__ __align__(16) float dls[256][4];     // d[j][i], one b128 per j
    __shared__ __align__(16) float Sls[4][128];
    __shared__ __align__(16) float Tls[4][128];     // act (phase A), then T
    __shared__ __align__(16) float Pls[4][128];     // P' (exp2-scaled)
    __shared__ __align__(16) float prels[4][128];   // pre
    __shared__ float cs;

    const int t  = threadIdx.x;
    const int b  = blockIdx.x >> 6;
    const int i0 = (blockIdx.x & 63) * 4;
    const int node0 = b * N_ + i0;

    // pairwise distances for this block's 4 i-rows
    {
        const int t2 = t & 255;
        const int half = t >> 8;
        const int il = t2 & 3;
        const int jb = t2 >> 2;
        const float* pb = positions + b * N_ * 3;
        const float pix = pb[(i0 + il) * 3 + 0];
        const float piy = pb[(i0 + il) * 3 + 1];
        const float piz = pb[(i0 + il) * 3 + 2];
        #pragma unroll
        for (int s = 0; s < 2; ++s) {
            int j = jb + 64 * (half * 2 + s);
            float dx = pix - pb[j * 3 + 0];
            float dy = piy - pb[j * 3 + 1];
            float dz = piz - pb[j * 3 + 2];
            float sq = dx * dx + dy * dy + dz * dz;
            dls[j][il] = (sq > 0.f) ? sqrtf(sq) : 0.f;
        }
    }
    if (t < 64) {   // cnt = sum_j mask[b][j]
        float mv = mask[b * N_ + t] + mask[b * N_ + 64 + t]
                 + mask[b * N_ + 128 + t] + mask[b * N_ + 192 + t];
        #pragma unroll
        for (int off = 32; off >= 1; off >>= 1) mv += __shfl_down(mv, off);
        if (t == 0) cs = mv;
    }

    // ---- phase A: P' and pre for own 4 rows (arena = split-K partials) ----
    const int kseg = t >> 5;
    const int c0   = (t & 31) * 4;
    float (*pls)[4][128] = (float (*)[4][128])arena;

    if (t < 128) {
        int r = t >> 5, col = (t & 31) * 4;
        *(float4*)(&Tls[r][col]) = *(const float4*)(node + (size_t)(node0 + r) * H_ + col);
    }
    __syncthreads();
    splitk_gemm(We1 + (size_t)(kseg * 8) * H_ + c0, Tls, pls, kseg, c0);
    __syncthreads();
    {
        const int n = t >> 7, c = t & 127;
        float s = 0.f;
        #pragma unroll
        for (int seg = 0; seg < 16; ++seg) s += pls[seg][n][c];
        Pls[n][c] = -LOG2E * (s + be1[c]);
    }
    __syncthreads();
    splitk_gemm(Wn1 + (size_t)(kseg * 8) * H_ + c0, Tls, pls, kseg, c0);
    __syncthreads();
    {
        const int n = t >> 7, c = t & 127;
        float s = 0.f;
        #pragma unroll
        for (int seg = 0; seg < 16; ++seg) s += pls[seg][n][c];
        prels[n][c] = s + bn1[c];
    }
    __syncthreads();    // Pls/prels visible; arena (pls) reads complete

    // ---- edge loop: thread = (jh, cg), register-carries all 4 i-rows ----
    const int jh  = t >> 5;          // 16 j-groups of 16 j each
    const int cg  = t & 31;
    const int c0e = cg * 4;

    float4 wd4 = *(const float4*)(We1 + (size_t)256 * H_ + c0e);
    wd4.x *= -LOG2E; wd4.y *= -LOG2E; wd4.z *= -LOG2E; wd4.w *= -LOG2E;

    float4 bse[4];
    #pragma unroll
    for (int i2 = 0; i2 < 4; ++i2)
        bse[i2] = *(const float4*)(&Pls[i2][c0e]);

    float4 acc[4];
    #pragma unroll
    for (int i2 = 0; i2 < 4; ++i2) acc[i2] = make_float4(0.f, 0.f, 0.f, 0.f);

    const float4* __restrict__ Qg4 = (const float4*)(Qv + (size_t)(b * N_) * H_);

    #pragma unroll 4
    for (int jl = 0; jl < 16; ++jl) {
        const int j = jh * 16 + jl;
        const float4 q  = Qg4[j * 32 + cg];              // global, L2-hit
        const float4 d4 = *(const float4*)(&dls[j][0]);  // b128 broadcast
        const float dd[4] = {d4.x, d4.y, d4.z, d4.w};
        #pragma unroll
        for (int i2 = 0; i2 < 4; ++i2) {
            float nx = fmaf(dd[i2], wd4.x, bse[i2].x + q.x);   // n = -log2e*x
            float ny = fmaf(dd[i2], wd4.y, bse[i2].y + q.y);
            float nz = fmaf(dd[i2], wd4.z, bse[i2].z + q.z);
            float nw = fmaf(dd[i2], wd4.w, bse[i2].w + q.w);
            acc[i2].x = fmaf(nx, __builtin_amdgcn_rcpf(1.0f + __builtin_amdgcn_exp2f(nx)), acc[i2].x);
            acc[i2].y = fmaf(ny, __builtin_amdgcn_rcpf(1.0f + __builtin_amdgcn_exp2f(ny)), acc[i2].y);
            acc[i2].z = fmaf(nz, __builtin_amdgcn_rcpf(1.0f + __builtin_amdgcn_exp2f(nz)), acc[i2].z);
            acc[i2].w = fmaf(nw, __builtin_amdgcn_rcpf(1.0f + __builtin_amdgcn_exp2f(nw)), acc[i2].w);
            // masked j: n* ~ +1e30 -> exp2=inf -> rcp=0 -> fma adds exact 0
        }
    }

    // jh-partial reduce: pq[jh][i][c] in arena (phase-A reads done, no sync
    // needed before writes — edge loop itself never touches arena)
    {
        float (*pq)[4][128] = (float (*)[4][128])arena;   // [16][4][128]
        #pragma unroll
        for (int i2 = 0; i2 < 4; ++i2)
            *(float4*)(&pq[jh][i2][c0e]) = acc[i2];
    }
    __syncthreads();
    const int i = t >> 7;             // wave-uniform row for reduces
    const float mi = mask[node0 + i];
    {
        const int c = t & 127;
        float (*pq)[4][128] = (float (*)[4][128])arena;
        float s = 0.f;
        #pragma unroll
        for (int seg = 0; seg < 16; ++seg) s += pq[seg][i][c];
        const float inv_cnt = __builtin_amdgcn_rcpf(fmaxf(cs, 1.0f));
        Sls[i][c] = (mi * inv_cnt * -LN2) * s;     // unscale exp2 domain
    }
    __syncthreads();

    // ---- epilogue: 3 split-K GEMMs, arena = partials ----
    // G1: T = S' @ We2 + mi*be2
    splitk_gemm(We2 + (size_t)(kseg * 8) * H_ + c0, Sls, pls, kseg, c0);
    __syncthreads();
    {
        const int c = t & 127;
        float s = 0.f;
        #pragma unroll
        for (int seg = 0; seg < 16; ++seg) s += pls[seg][i][c];
        Tls[i][c] = fmaf(mi, be2[c], s);
    }
    __syncthreads();

    // G2: hidden = silu(pre + T @ Wn1[128:])
    splitk_gemm(Wn1 + (size_t)(128 + kseg * 8) * H_ + c0, Tls, pls, kseg, c0);
    __syncthreads();
    {
        const int c = t & 127;
        float s = 0.f;
        #pragma unroll
        for (int seg = 0; seg < 16; ++seg) s += pls[seg][i][c];
        Sls[i][c] = silu_fast(prels[i][c] + s);    // reuse Sls as hidden
    }
    __syncthreads();

    // G3: out = node + mi * (hidden @ Wn2 + bn2)
    splitk_gemm(Wn2 + (size_t)(kseg * 8) * H_ + c0, Sls, pls, kseg, c0);
    __syncthreads();
    {
        const int c = t & 127;
        float s = 0.f;
        #pragma unroll
        for (int seg = 0; seg < 16; ++seg) s += pls[seg][i][c];
        const size_t idx = (size_t)(node0 + i) * H_ + c;
        out[idx] = node[idx] + mi * (s + bn2[c]);
    }
}

extern "C" void kernel_launch(void* const* d_in, const int* in_sizes, int n_in,
                              void* d_out, int out_size, void* d_ws, size_t ws_size,
                              hipStream_t stream)
{
    const float* node      = (const float*)d_in[0];
    const float* positions = (const float*)d_in[1];
    const float* mask      = (const float*)d_in[2];
    const float* We1       = (const float*)d_in[3];
    const float* be1       = (const float*)d_in[4];
    const float* We2       = (const float*)d_in[5];
    const float* be2       = (const float*)d_in[6];
    const float* Wn1       = (const float*)d_in[7];
    const float* bn1       = (const float*)d_in[8];
    const float* Wn2       = (const float*)d_in[9];
    const float* bn2       = (const float*)d_in[10];
    float* out = (float*)d_out;

    float* Q = (float*)d_ws;                   // 1 MB workspace

    k1q<<<512, 512, 0, stream>>>(node, We1, mask, Q);
    k2 <<<512, 512, 0, stream>>>(Q, We1, be1, positions, mask, node,
                                 We2, be2, Wn1, bn1, Wn2, bn2, out);
}